// Round 1
// baseline (534.228 us; speedup 1.0000x reference)
//
#include <hip/hip_runtime.h>
#include <hip/hip_bf16.h>

#define E_EDGES   400000
#define DE        128
#define DRBF      16
#define NG        256
#define TE        64
#define NTILES    (E_EDGES / TE)
#define SILU_SC   (1.0f / 0.6f)

static_assert(E_EDGES % TE == 0, "tile divisibility");

typedef short bf16x8 __attribute__((ext_vector_type(8)));
typedef float f32x4  __attribute__((ext_vector_type(4)));

__device__ __forceinline__ unsigned int f2bf(float x) {
    union { float f; unsigned int u; } v; v.f = x;
    return (v.u + 0x7FFFu + ((v.u >> 16) & 1u)) >> 16;   // RNE f32->bf16
}

// ---------------- kernel 1: edges-per-graph histogram ----------------
__global__ void gn_count(const int* __restrict__ ei0, const int* __restrict__ batch,
                         int* __restrict__ counts) {
    __shared__ int hist[NG];
    const int tid = threadIdx.x;
    hist[tid] = 0;
    __syncthreads();
    for (int e = blockIdx.x * 256 + tid; e < E_EDGES; e += gridDim.x * 256)
        atomicAdd(&hist[batch[ei0[e]]], 1);
    __syncthreads();
    if (hist[tid]) atomicAdd(&counts[tid], hist[tid]);
}

// ---------------- kernel 2: fused MLP + scores + segment outer-product ----------------
__global__ __launch_bounds__(256) void gn_main(
    const float* __restrict__ edge_emb, const float* __restrict__ dvec,
    const float* __restrict__ rbf, const float* __restrict__ W1,
    const float* __restrict__ W2, const float* __restrict__ Wr,
    const float* __restrict__ Wo, const int* __restrict__ ei0,
    const int* __restrict__ batch, const int* __restrict__ counts,
    float* __restrict__ Lws)
{
    __shared__ __align__(16) unsigned char sA[TE * DE * 2];   // 16KB: emb tile, then act tile (bf16, swizzled)
    __shared__ __align__(16) unsigned char sR[TE * 32 * 2];   // 4KB: rbf tile padded to K=32 (bf16, swizzled)
    __shared__ float sScore[4][TE];                           // per-wave partial row scores
    __shared__ float sLacc[NG * 9];                           // per-block graph accumulators

    const int tid  = threadIdx.x;
    const int lane = tid & 63;
    const int wid  = tid >> 6;
    const int lq   = lane >> 4;    // 16-lane group
    const int lr   = lane & 15;
    const int wcol = wid * 32;     // this wave's 32 output columns

    for (int i = tid; i < NG * 9; i += 256) sLacc[i] = 0.0f;

    // ---- prologue: weight fragments resident in registers (whole kernel) ----
    bf16x8 b1[2][4], b2[2][4], brf[2];
    #pragma unroll
    for (int n = 0; n < 2; ++n) {
        const int col = wcol + n * 16 + lr;
        #pragma unroll
        for (int kt = 0; kt < 4; ++kt) {
            bf16x8 v1, v2;
            #pragma unroll
            for (int j = 0; j < 8; ++j) {
                const int k = kt * 32 + lq * 8 + j;
                v1[j] = (short)f2bf(W1[k * DE + col]);
                v2[j] = (short)f2bf(W2[k * DE + col]);
            }
            b1[n][kt] = v1;
            b2[n][kt] = v2;
        }
        const float wo = Wo[col];                 // fold W_out into W_rbf
        bf16x8 vr;
        #pragma unroll
        for (int j = 0; j < 8; ++j) {
            const int k = lq * 8 + j;
            vr[j] = (k < DRBF) ? (short)f2bf(Wr[k * DE + col] * wo) : (short)0;
        }
        brf[n] = vr;
    }

    const f32x4 zero4 = {0.0f, 0.0f, 0.0f, 0.0f};

    for (int t = blockIdx.x; t < NTILES; t += gridDim.x) {
        const int e0 = t * TE;

        // ---- stage edge_emb tile -> sA (bf16, XOR-swizzled rows) ----
        #pragma unroll
        for (int i = 0; i < 8; ++i) {
            const int f4  = i * 256 + tid;
            const int row = f4 >> 5;
            const int c4  = (f4 & 31) << 2;
            const float4 v = *reinterpret_cast<const float4*>(edge_emb + (size_t)(e0 + row) * DE + c4);
            uint2 p;
            p.x = f2bf(v.x) | (f2bf(v.y) << 16);
            p.y = f2bf(v.z) | (f2bf(v.w) << 16);
            const int byo = (row * 256 + c4 * 2) ^ ((row & 7) << 4);
            *reinterpret_cast<uint2*>(sA + byo) = p;
        }
        // ---- stage rbf tile -> sR ([64][32] bf16, cols 16..31 zero) ----
        {
            const int row = tid >> 2, q = tid & 3;
            const int byo = (row * 64 + q * 16) ^ ((row & 3) << 4);
            uint4 p = make_uint4(0u, 0u, 0u, 0u);
            if (q < 2) {
                const float4 a = *reinterpret_cast<const float4*>(rbf + (size_t)(e0 + row) * DRBF + q * 8);
                const float4 b = *reinterpret_cast<const float4*>(rbf + (size_t)(e0 + row) * DRBF + q * 8 + 4);
                p.x = f2bf(a.x) | (f2bf(a.y) << 16);
                p.y = f2bf(a.z) | (f2bf(a.w) << 16);
                p.z = f2bf(b.x) | (f2bf(b.y) << 16);
                p.w = f2bf(b.z) | (f2bf(b.w) << 16);
            }
            *reinterpret_cast<uint4*>(sR + byo) = p;
        }
        __syncthreads();

        // ---- rbf_emb' = rbf @ (W_rbf * W_out) via K=32 MFMA (top 16 k zero) ----
        f32x4 accR[4][2];
        #pragma unroll
        for (int m = 0; m < 4; ++m) {
            const int row = m * 16 + lr;
            const int byo = (row * 64 + lq * 16) ^ ((row & 3) << 4);
            const bf16x8 a = *reinterpret_cast<const bf16x8*>(sR + byo);
            #pragma unroll
            for (int n = 0; n < 2; ++n)
                accR[m][n] = __builtin_amdgcn_mfma_f32_16x16x32_bf16(a, brf[n], zero4, 0, 0, 0);
        }

        // ---- GEMM1: h = emb @ W1 ----
        f32x4 acc[4][2];
        #pragma unroll
        for (int m = 0; m < 4; ++m)
            #pragma unroll
            for (int n = 0; n < 2; ++n) acc[m][n] = zero4;
        #pragma unroll
        for (int kt = 0; kt < 4; ++kt) {
            bf16x8 a[4];
            #pragma unroll
            for (int m = 0; m < 4; ++m) {
                const int row = m * 16 + lr;
                const int byo = (row * 256 + kt * 64 + lq * 16) ^ ((row & 7) << 4);
                a[m] = *reinterpret_cast<const bf16x8*>(sA + byo);
            }
            #pragma unroll
            for (int m = 0; m < 4; ++m)
                #pragma unroll
                for (int n = 0; n < 2; ++n)
                    acc[m][n] = __builtin_amdgcn_mfma_f32_16x16x32_bf16(a[m], b1[n][kt], acc[m][n], 0, 0, 0);
        }
        __syncthreads();   // all GEMM1 reads of sA done

        // ---- silu*(1/0.6) -> bf16, scatter back into sA (C-layout scatter) ----
        #pragma unroll
        for (int m = 0; m < 4; ++m)
            #pragma unroll
            for (int n = 0; n < 2; ++n)
                #pragma unroll
                for (int r = 0; r < 4; ++r) {
                    const float h  = acc[m][n][r];
                    const float av = h / (1.0f + __expf(-h)) * SILU_SC;
                    const int row  = m * 16 + lq * 4 + r;
                    const int col  = wcol + n * 16 + lr;
                    const int byo  = (row * 256 + col * 2) ^ ((row & 7) << 4);
                    *reinterpret_cast<unsigned short*>(sA + byo) = (unsigned short)f2bf(av);
                }
        __syncthreads();

        // ---- GEMM2: x = act @ W2 ----
        f32x4 acc2[4][2];
        #pragma unroll
        for (int m = 0; m < 4; ++m)
            #pragma unroll
            for (int n = 0; n < 2; ++n) acc2[m][n] = zero4;
        #pragma unroll
        for (int kt = 0; kt < 4; ++kt) {
            bf16x8 a[4];
            #pragma unroll
            for (int m = 0; m < 4; ++m) {
                const int row = m * 16 + lr;
                const int byo = (row * 256 + kt * 64 + lq * 16) ^ ((row & 7) << 4);
                a[m] = *reinterpret_cast<const bf16x8*>(sA + byo);
            }
            #pragma unroll
            for (int m = 0; m < 4; ++m)
                #pragma unroll
                for (int n = 0; n < 2; ++n)
                    acc2[m][n] = __builtin_amdgcn_mfma_f32_16x16x32_bf16(a[m], b2[n][kt], acc2[m][n], 0, 0, 0);
        }

        // ---- per-row score = sum_col x * rbf_emb' ; butterfly over 16 lanes ----
        #pragma unroll
        for (int m = 0; m < 4; ++m) {
            f32x4 p;
            #pragma unroll
            for (int r = 0; r < 4; ++r)
                p[r] = acc2[m][0][r] * accR[m][0][r] + acc2[m][1][r] * accR[m][1][r];
            #pragma unroll
            for (int off = 1; off < 16; off <<= 1)
                #pragma unroll
                for (int r = 0; r < 4; ++r)
                    p[r] += __shfl_xor(p[r], off, 64);
            if (lr == 0)
                #pragma unroll
                for (int r = 0; r < 4; ++r)
                    sScore[wid][m * 16 + lq * 4 + r] = p[r];
        }
        __syncthreads();

        // ---- per-edge epilogue: score/num_edges * unit_i * dvec_j into sLacc ----
        if (tid < TE) {
            const int e = e0 + tid;
            float s = sScore[0][tid] + sScore[1][tid] + sScore[2][tid] + sScore[3][tid];
            const int g = batch[ei0[e]];
            s /= (float)counts[g];
            const float dx = dvec[(size_t)3 * e];
            const float dy = dvec[(size_t)3 * e + 1];
            const float dz = dvec[(size_t)3 * e + 2];
            const float rn = 1.0f / sqrtf(dx * dx + dy * dy + dz * dz);
            const float sx = s * dx * rn, sy = s * dy * rn, sz = s * dz * rn;
            float* L = sLacc + g * 9;
            atomicAdd(L + 0, sx * dx); atomicAdd(L + 1, sx * dy); atomicAdd(L + 2, sx * dz);
            atomicAdd(L + 3, sy * dx); atomicAdd(L + 4, sy * dy); atomicAdd(L + 5, sy * dz);
            atomicAdd(L + 6, sz * dx); atomicAdd(L + 7, sz * dy); atomicAdd(L + 8, sz * dz);
        }
        __syncthreads();   // protect sScore/sA/sR before next tile's staging
    }

    for (int i = tid; i < NG * 9; i += 256)
        atomicAdd(&Lws[i], sLacc[i]);
}

// ---------------- kernel 3: symmetrize ----------------
__global__ void gn_finalize(const float* __restrict__ Lws, float* __restrict__ out) {
    const int i = blockIdx.x * 256 + threadIdx.x;
    if (i < NG * 9) {
        const int g = i / 9, rem = i % 9, r = rem / 3, c = rem % 3;
        out[i] = 0.5f * (Lws[i] + Lws[g * 9 + c * 3 + r]);
    }
}

extern "C" void kernel_launch(void* const* d_in, const int* in_sizes, int n_in,
                              void* d_out, int out_size, void* d_ws, size_t ws_size,
                              hipStream_t stream) {
    const float* edge_emb = (const float*)d_in[0];
    const float* dvec     = (const float*)d_in[1];
    // d_in[2] = lattice: only its leading dim (256) is used -> constant
    const float* rbf      = (const float*)d_in[3];
    const float* W1       = (const float*)d_in[4];
    const float* W2       = (const float*)d_in[5];
    const float* Wr       = (const float*)d_in[6];
    const float* Wo       = (const float*)d_in[7];
    const int*   ei0      = (const int*)d_in[8];   // row 0 of (2,E)
    const int*   batch    = (const int*)d_in[9];
    float* out = (float*)d_out;

    int*   counts = (int*)d_ws;                         // 256 ints
    float* Lws    = (float*)((char*)d_ws + 1024);       // 2304 floats

    hipMemsetAsync(d_ws, 0, 1024 + NG * 9 * sizeof(float), stream);
    gn_count<<<256, 256, 0, stream>>>(ei0, batch, counts);
    gn_main<<<1024, 256, 0, stream>>>(edge_emb, dvec, rbf, W1, W2, Wr, Wo,
                                      ei0, batch, counts, Lws);
    gn_finalize<<<9, 256, 0, stream>>>(Lws, out);
}

// Round 2
// 491.431 us; speedup vs baseline: 1.0871x; 1.0871x over previous
//
#include <hip/hip_runtime.h>
#include <hip/hip_bf16.h>

#define E_EDGES 400000
#define DE      128
#define DRBF    16
#define NG      256
#define TE      64
#define NTILES  (E_EDGES / TE)
#define SILU_SC (1.0f / 0.6f)
#define GRID_MAIN 1568

static_assert(E_EDGES % TE == 0, "tile divisibility");

typedef short bf16x8 __attribute__((ext_vector_type(8)));
typedef float f32x4  __attribute__((ext_vector_type(4)));

__device__ __forceinline__ unsigned int f2bf(float x) {
    union { float f; unsigned int u; } v; v.f = x;
    return (v.u + 0x7FFFu + ((v.u >> 16) & 1u)) >> 16;   // RNE f32->bf16
}
__device__ __forceinline__ float silu_s(float h) {
    return h / (1.0f + __expf(-h)) * SILU_SC;
}

// ws layout (bytes): [0,1024) counts | [1024,10240) Lws | [10240,43008) fragW1 | [43008,51200) fragG

// ---------------- kernel A: one-time weight-fragment + G precompute ----------------
// G[k][j] = sum_c W2[k][c] * Wr[j][c] * Wo[c]  (score = act . (rbf @ G^T))
__global__ __launch_bounds__(256) void gn_prep(
    const float* __restrict__ W1, const float* __restrict__ W2,
    const float* __restrict__ Wr, const float* __restrict__ Wo,
    unsigned char* __restrict__ fragW1, unsigned char* __restrict__ fragG)
{
    const int tid = threadIdx.x, lane = tid & 63, wid = tid >> 6;
    const int lq = lane >> 4, lr = lane & 15, wcol = wid * 32;
    #pragma unroll
    for (int n = 0; n < 2; ++n) {
        const int col = wcol + n * 16 + lr;
        #pragma unroll
        for (int kt = 0; kt < 4; ++kt) {
            bf16x8 v;
            #pragma unroll
            for (int j = 0; j < 8; ++j)
                v[j] = (short)f2bf(W1[(kt * 32 + lq * 8 + j) * DE + col]);
            *reinterpret_cast<bf16x8*>(fragW1 + tid * 128 + (n * 4 + kt) * 16) = v;
        }
        bf16x8 vg = {0, 0, 0, 0, 0, 0, 0, 0};
        if (lq < 2) {
            #pragma unroll
            for (int jj = 0; jj < 8; ++jj) {
                const int j = lq * 8 + jj;
                f32x4 a4 = {0.0f, 0.0f, 0.0f, 0.0f};
                for (int c4 = 0; c4 < 32; ++c4) {
                    const f32x4 w2 = *reinterpret_cast<const f32x4*>(W2 + col * DE + c4 * 4);
                    const f32x4 wr = *reinterpret_cast<const f32x4*>(Wr + j * DE + c4 * 4);
                    const f32x4 wo = *reinterpret_cast<const f32x4*>(Wo + c4 * 4);
                    a4 += w2 * wr * wo;
                }
                vg[jj] = (short)f2bf(a4[0] + a4[1] + a4[2] + a4[3]);
            }
        }
        *reinterpret_cast<bf16x8*>(fragG + tid * 32 + n * 16) = vg;
    }
}

// ---------------- kernel B: edges-per-graph histogram ----------------
__global__ void gn_count(const int* __restrict__ ei0, const int* __restrict__ batch,
                         int* __restrict__ counts) {
    __shared__ int hist[NG];
    const int tid = threadIdx.x;
    hist[tid] = 0;
    __syncthreads();
    for (int e = blockIdx.x * 256 + tid; e < E_EDGES; e += gridDim.x * 256)
        atomicAdd(&hist[batch[ei0[e]]], 1);
    __syncthreads();
    if (hist[tid]) atomicAdd(&counts[tid], hist[tid]);
}

// ---------------- kernel C: fused GEMM1 + score + segment outer-product ----------------
__global__ __launch_bounds__(256, 3) void gn_main(
    const float* __restrict__ edge_emb, const float* __restrict__ dvec,
    const float* __restrict__ rbf, const int* __restrict__ ei0,
    const int* __restrict__ batch, const int* __restrict__ counts,
    const unsigned char* __restrict__ fragW1, const unsigned char* __restrict__ fragG,
    float* __restrict__ Lws)
{
    __shared__ __align__(16) unsigned char sA[2][TE * DE * 2];     // 2 x 16KB emb tiles (bf16, swizzled)
    __shared__ __align__(16) unsigned char sR[2][TE * DRBF * 2];   // 2 x 2KB rbf tiles (bf16)
    __shared__ float sS[2][4][TE];                                 // per-wave partial scores (dbuf)
    __shared__ float sLacc[NG * 9];                                // per-block graph accumulators

    const int tid = threadIdx.x, lane = tid & 63, wid = tid >> 6;
    const int lq = lane >> 4, lr = lane & 15;

    for (int i = tid; i < NG * 9; i += 256) sLacc[i] = 0.0f;

    // weight fragments (precomputed, coalesced 16B loads)
    bf16x8 b1[2][4], bG[2];
    #pragma unroll
    for (int n = 0; n < 2; ++n) {
        #pragma unroll
        for (int kt = 0; kt < 4; ++kt)
            b1[n][kt] = *reinterpret_cast<const bf16x8*>(fragW1 + tid * 128 + (n * 4 + kt) * 16);
        bG[n] = *reinterpret_cast<const bf16x8*>(fragG + tid * 32 + n * 16);
    }

    const f32x4 zero4 = {0.0f, 0.0f, 0.0f, 0.0f};

    // ---- prologue: stage first tile into buffer 0 ----
    {
        const int t0 = blockIdx.x;
        if (t0 < NTILES) {
            const size_t e0 = (size_t)t0 * TE;
            #pragma unroll
            for (int i = 0; i < 8; ++i) {
                const int f4 = i * 256 + tid, row = f4 >> 5, c4 = (f4 & 31) << 2;
                const float4 v = *reinterpret_cast<const float4*>(edge_emb + (e0 + row) * DE + c4);
                uint2 p; p.x = f2bf(v.x) | (f2bf(v.y) << 16); p.y = f2bf(v.z) | (f2bf(v.w) << 16);
                *reinterpret_cast<uint2*>(&sA[0][(row * 256 + c4 * 2) ^ ((row & 7) << 4)]) = p;
            }
            const int row = tid >> 2, ch = tid & 3;
            const float4 v = *reinterpret_cast<const float4*>(rbf + (e0 + row) * DRBF + ch * 4);
            uint2 p; p.x = f2bf(v.x) | (f2bf(v.y) << 16); p.y = f2bf(v.z) | (f2bf(v.w) << 16);
            *reinterpret_cast<uint2*>(&sR[0][row * 32 + ch * 8]) = p;
        }
    }
    __syncthreads();

    int cur = 0;
    for (int t = blockIdx.x; t < NTILES; t += GRID_MAIN) {
        const int tn = t + GRID_MAIN;
        const bool pf = tn < NTILES;

        // ---- issue next tile's global loads EARLY (latency hides under GEMM) ----
        float4 ve[8], vr;
        if (pf) {
            const size_t e0n = (size_t)tn * TE;
            #pragma unroll
            for (int i = 0; i < 8; ++i) {
                const int f4 = i * 256 + tid, row = f4 >> 5, c4 = (f4 & 31) << 2;
                ve[i] = *reinterpret_cast<const float4*>(edge_emb + (e0n + row) * DE + c4);
            }
            vr = *reinterpret_cast<const float4*>(rbf + (e0n + (tid >> 2)) * DRBF + (tid & 3) * 4);
        }
        // ---- epilogue gather chain issued early too ----
        int g = 0; float cinv = 0.0f, dx = 0.0f, dy = 0.0f, dz = 0.0f;
        if (tid < TE) {
            const size_t e = (size_t)t * TE + tid;
            g = batch[ei0[e]];
            cinv = 1.0f / (float)counts[g];
            dx = dvec[3 * e]; dy = dvec[3 * e + 1]; dz = dvec[3 * e + 2];
        }

        // ---- GEMM1: h = emb @ W1 ----
        f32x4 acc[4][2];
        #pragma unroll
        for (int m = 0; m < 4; ++m) { acc[m][0] = zero4; acc[m][1] = zero4; }
        #pragma unroll
        for (int kt = 0; kt < 4; ++kt) {
            bf16x8 a[4];
            #pragma unroll
            for (int m = 0; m < 4; ++m) {
                const int row = m * 16 + lr;
                a[m] = *reinterpret_cast<const bf16x8*>(
                    &sA[cur][(row * 256 + kt * 64 + lq * 16) ^ ((row & 7) << 4)]);
            }
            #pragma unroll
            for (int m = 0; m < 4; ++m) {
                acc[m][0] = __builtin_amdgcn_mfma_f32_16x16x32_bf16(a[m], b1[0][kt], acc[m][0], 0, 0, 0);
                acc[m][1] = __builtin_amdgcn_mfma_f32_16x16x32_bf16(a[m], b1[1][kt], acc[m][1], 0, 0, 0);
            }
        }

        // ---- per-m: y = rbf @ G^T (K=32, top half zero) ; score = silu(h)*y ; butterfly ----
        #pragma unroll
        for (int m = 0; m < 4; ++m) {
            bf16x8 aR = {0, 0, 0, 0, 0, 0, 0, 0};
            if (lq < 2)
                aR = *reinterpret_cast<const bf16x8*>(&sR[cur][(m * 16 + lr) * 32 + lq * 16]);
            const f32x4 y0 = __builtin_amdgcn_mfma_f32_16x16x32_bf16(aR, bG[0], zero4, 0, 0, 0);
            const f32x4 y1 = __builtin_amdgcn_mfma_f32_16x16x32_bf16(aR, bG[1], zero4, 0, 0, 0);
            f32x4 p;
            #pragma unroll
            for (int r = 0; r < 4; ++r)
                p[r] = silu_s(acc[m][0][r]) * y0[r] + silu_s(acc[m][1][r]) * y1[r];
            #pragma unroll
            for (int off = 1; off < 16; off <<= 1)
                #pragma unroll
                for (int r = 0; r < 4; ++r)
                    p[r] += __shfl_xor(p[r], off, 64);
            if (lr == 0) {
                #pragma unroll
                for (int r = 0; r < 4; ++r)
                    sS[cur][wid][m * 16 + lq * 4 + r] = p[r];
            }
        }

        // ---- write prefetched tile into the other buffer (loads already in flight) ----
        if (pf) {
            #pragma unroll
            for (int i = 0; i < 8; ++i) {
                const int f4 = i * 256 + tid, row = f4 >> 5, c4 = (f4 & 31) << 2;
                uint2 p; p.x = f2bf(ve[i].x) | (f2bf(ve[i].y) << 16);
                p.y = f2bf(ve[i].z) | (f2bf(ve[i].w) << 16);
                *reinterpret_cast<uint2*>(&sA[cur ^ 1][(row * 256 + c4 * 2) ^ ((row & 7) << 4)]) = p;
            }
            const int row = tid >> 2, ch = tid & 3;
            uint2 p; p.x = f2bf(vr.x) | (f2bf(vr.y) << 16); p.y = f2bf(vr.z) | (f2bf(vr.w) << 16);
            *reinterpret_cast<uint2*>(&sR[cur ^ 1][row * 32 + ch * 8]) = p;
        }

        __syncthreads();   // the ONE barrier: sA[nxt]/sR[nxt] ready, sS[cur] ready

        // ---- per-edge epilogue ----
        if (tid < TE) {
            float s = (sS[cur][0][tid] + sS[cur][1][tid] + sS[cur][2][tid] + sS[cur][3][tid]) * cinv;
            const float rn = 1.0f / sqrtf(dx * dx + dy * dy + dz * dz);
            const float sx = s * dx * rn, sy = s * dy * rn, sz = s * dz * rn;
            float* L = sLacc + g * 9;
            atomicAdd(L + 0, sx * dx); atomicAdd(L + 1, sx * dy); atomicAdd(L + 2, sx * dz);
            atomicAdd(L + 3, sy * dx); atomicAdd(L + 4, sy * dy); atomicAdd(L + 5, sy * dz);
            atomicAdd(L + 6, sz * dx); atomicAdd(L + 7, sz * dy); atomicAdd(L + 8, sz * dz);
        }
        cur ^= 1;
    }

    __syncthreads();
    for (int i = tid; i < NG * 9; i += 256)
        atomicAdd(&Lws[i], sLacc[i]);
}

// ---------------- kernel D: symmetrize ----------------
__global__ void gn_finalize(const float* __restrict__ Lws, float* __restrict__ out) {
    const int i = blockIdx.x * 256 + threadIdx.x;
    if (i < NG * 9) {
        const int g = i / 9, rem = i % 9, r = rem / 3, c = rem % 3;
        out[i] = 0.5f * (Lws[i] + Lws[g * 9 + c * 3 + r]);
    }
}

extern "C" void kernel_launch(void* const* d_in, const int* in_sizes, int n_in,
                              void* d_out, int out_size, void* d_ws, size_t ws_size,
                              hipStream_t stream) {
    const float* edge_emb = (const float*)d_in[0];
    const float* dvec     = (const float*)d_in[1];
    const float* rbf      = (const float*)d_in[3];
    const float* W1       = (const float*)d_in[4];
    const float* W2       = (const float*)d_in[5];
    const float* Wr       = (const float*)d_in[6];
    const float* Wo       = (const float*)d_in[7];
    const int*   ei0      = (const int*)d_in[8];
    const int*   batch    = (const int*)d_in[9];
    float* out = (float*)d_out;

    int*   counts = (int*)d_ws;                               // [0,1024)
    float* Lws    = (float*)((char*)d_ws + 1024);             // [1024,10240)
    unsigned char* fragW1 = (unsigned char*)d_ws + 10240;     // 32KB
    unsigned char* fragG  = (unsigned char*)d_ws + 43008;     // 8KB

    hipMemsetAsync(d_ws, 0, 10240, stream);
    gn_prep<<<1, 256, 0, stream>>>(W1, W2, Wr, Wo, fragW1, fragG);
    gn_count<<<256, 256, 0, stream>>>(ei0, batch, counts);
    gn_main<<<GRID_MAIN, 256, 0, stream>>>(edge_emb, dvec, rbf, ei0, batch, counts,
                                           fragW1, fragG, Lws);
    gn_finalize<<<9, 256, 0, stream>>>(Lws, out);
}

// Round 3
// 405.143 us; speedup vs baseline: 1.3186x; 1.2130x over previous
//
#include <hip/hip_runtime.h>
#include <hip/hip_bf16.h>

#define E_EDGES 400000
#define DE      128
#define DRBF    16
#define NG      256
#define MT      16                    // edges per wave-microtile
#define NMT     (E_EDGES / MT)        // 25000
#define SILU_SC (1.0f / 0.6f)
#define GRID_MAIN 768

static_assert(E_EDGES % MT == 0, "tile divisibility");

typedef short bf16x8 __attribute__((ext_vector_type(8)));
typedef float f32x4  __attribute__((ext_vector_type(4)));

__device__ __forceinline__ unsigned int f2bf(float x) {
    union { float f; unsigned int u; } v; v.f = x;
    return (v.u + 0x7FFFu + ((v.u >> 16) & 1u)) >> 16;   // RNE f32->bf16
}
__device__ __forceinline__ bf16x8 cvt8(f32x4 a, f32x4 b) {
    bf16x8 r;
    #pragma unroll
    for (int j = 0; j < 4; ++j) {
        r[j]     = (short)f2bf(a[j]);
        r[4 + j] = (short)f2bf(b[j]);
    }
    return r;
}
__device__ __forceinline__ float silu_s(float h) {
    return h / (1.0f + __expf(-h)) * SILU_SC;
}

// ws layout (bytes): [0,1024) counts | [1024,10240) Lws | [10240,43008) fragW1 | [43008,51200) fragG

// ---------------- kernel A: weight fragments + G precompute (parallel: 32 blocks) ----------------
// G[k][j] = sum_c W2[k][c] * Wr[j][c] * Wo[c]  ;  score = act . (rbf @ G^T)
__global__ void gn_prep(const float* __restrict__ W1, const float* __restrict__ W2,
                        const float* __restrict__ Wr, const float* __restrict__ Wo,
                        unsigned char* __restrict__ fragW1, unsigned char* __restrict__ fragG)
{
    const int lane = threadIdx.x;          // 64 threads
    const int b = blockIdx.x;              // 32 blocks: b = n*4 + kt
    const int n = b >> 2, kt = b & 3;
    const int lq = lane >> 4, lr = lane & 15;

    bf16x8 v;
    #pragma unroll
    for (int j = 0; j < 8; ++j)
        v[j] = (short)f2bf(W1[(kt * 32 + lq * 8 + j) * DE + n * 16 + lr]);
    *reinterpret_cast<bf16x8*>(fragW1 + ((size_t)(b * 64 + lane)) * 16) = v;

    if (kt == 0) {
        bf16x8 vg = {0, 0, 0, 0, 0, 0, 0, 0};
        if (lq < 2) {
            const float* w2row = W2 + (n * 16 + lr) * DE;
            #pragma unroll
            for (int jj = 0; jj < 8; ++jj) {
                const float* wrrow = Wr + (lq * 8 + jj) * DE;
                f32x4 a4 = {0.0f, 0.0f, 0.0f, 0.0f};
                for (int c4 = 0; c4 < 32; ++c4)
                    a4 += *reinterpret_cast<const f32x4*>(w2row + c4 * 4)
                        * *reinterpret_cast<const f32x4*>(wrrow + c4 * 4)
                        * *reinterpret_cast<const f32x4*>(Wo + c4 * 4);
                vg[jj] = (short)f2bf(a4[0] + a4[1] + a4[2] + a4[3]);
            }
        }
        *reinterpret_cast<bf16x8*>(fragG + ((size_t)(n * 64 + lane)) * 16) = vg;
    }
}

// ---------------- kernel B: edges-per-graph histogram ----------------
__global__ void gn_count(const int* __restrict__ ei0, const int* __restrict__ batch,
                         int* __restrict__ counts) {
    __shared__ int hist[NG];
    const int tid = threadIdx.x;
    hist[tid] = 0;
    __syncthreads();
    for (int e = blockIdx.x * 256 + tid; e < E_EDGES; e += gridDim.x * 256)
        atomicAdd(&hist[batch[ei0[e]]], 1);
    __syncthreads();
    if (hist[tid]) atomicAdd(&counts[tid], hist[tid]);
}

// ---------------- kernel C: fused GEMM1 + score + segment outer-product ----------------
// Each WAVE independently owns 16 edges x all 128 cols: A-frags loaded directly
// from global (each element exactly once), W1 frags register-resident, no LDS
// staging, no barriers in the hot loop.
__global__ __launch_bounds__(256, 2) void gn_main(
    const float* __restrict__ edge_emb, const float* __restrict__ dvec,
    const float* __restrict__ rbf, const int* __restrict__ ei0,
    const int* __restrict__ batch, const int* __restrict__ counts,
    const unsigned char* __restrict__ fragW1, const unsigned char* __restrict__ fragG,
    float* __restrict__ Lws)
{
    __shared__ float sLacc[NG * 9];    // per-block graph accumulators
    __shared__ float sSc[4][16];       // per-wave score relay (wave-local, no barrier)

    const int tid = threadIdx.x, lane = tid & 63, wid = tid >> 6;
    const int lq = lane >> 4, lr = lane & 15;

    for (int i = tid; i < NG * 9; i += 256) sLacc[i] = 0.0f;

    // W1 fragments: 128 VGPRs, resident for the whole kernel (coalesced 16B loads)
    bf16x8 b1[8][4];
    #pragma unroll
    for (int n = 0; n < 8; ++n)
        #pragma unroll
        for (int kt = 0; kt < 4; ++kt)
            b1[n][kt] = *reinterpret_cast<const bf16x8*>(fragW1 + ((size_t)((n * 4 + kt) * 64 + lane)) * 16);
    __syncthreads();   // sLacc initialized

    const f32x4 zero4 = {0.0f, 0.0f, 0.0f, 0.0f};
    const int gw = blockIdx.x * 4 + wid;
    const int nw = GRID_MAIN * 4;

    for (int mt = gw; mt < NMT; mt += nw) {
        const size_t e0 = (size_t)mt * MT;

        // ---- epilogue operands prefetched early (independent of GEMM) ----
        int g = 0; float cinv = 0.0f, dx = 0.0f, dy = 0.0f, dz = 0.0f;
        if (lane < 16) {
            const size_t e = e0 + lane;
            g = batch[ei0[e]];
            cinv = 1.0f / (float)counts[g];
            dx = dvec[3 * e]; dy = dvec[3 * e + 1]; dz = dvec[3 * e + 2];
        }

        // ---- rbf fragment: direct per-lane load (K=16 real, upper 16 zero) ----
        bf16x8 aR = {0, 0, 0, 0, 0, 0, 0, 0};
        if (lq < 2) {
            const float* rp = rbf + (e0 + lr) * DRBF + lq * 8;
            aR = cvt8(*reinterpret_cast<const f32x4*>(rp),
                      *reinterpret_cast<const f32x4*>(rp + 4));
        }

        // ---- GEMM1: h = emb @ W1, A-frags straight from HBM ----
        f32x4 acc[8];
        #pragma unroll
        for (int n = 0; n < 8; ++n) acc[n] = zero4;
        const float* ap = edge_emb + (e0 + lr) * DE + lq * 8;
        #pragma unroll
        for (int kt = 0; kt < 4; ++kt) {
            const bf16x8 a = cvt8(*reinterpret_cast<const f32x4*>(ap + kt * 32),
                                  *reinterpret_cast<const f32x4*>(ap + kt * 32 + 4));
            #pragma unroll
            for (int n = 0; n < 8; ++n)
                acc[n] = __builtin_amdgcn_mfma_f32_16x16x32_bf16(a, b1[n][kt], acc[n], 0, 0, 0);
        }

        // ---- score: p = sum_n silu(h_n) * (rbf @ G^T)_n ; butterfly over 16 lanes ----
        f32x4 p = zero4;
        #pragma unroll
        for (int n = 0; n < 8; ++n) {
            const bf16x8 bg = *reinterpret_cast<const bf16x8*>(fragG + ((size_t)(n * 64 + lane)) * 16);
            const f32x4 y = __builtin_amdgcn_mfma_f32_16x16x32_bf16(aR, bg, zero4, 0, 0, 0);
            #pragma unroll
            for (int r = 0; r < 4; ++r)
                p[r] += silu_s(acc[n][r]) * y[r];
        }
        #pragma unroll
        for (int off = 1; off < 16; off <<= 1)
            #pragma unroll
            for (int r = 0; r < 4; ++r)
                p[r] += __shfl_xor(p[r], off, 64);

        // relay scores to lanes 0..15 (same wave: ds-ordering only, no barrier)
        if (lr == 0) {
            #pragma unroll
            for (int r = 0; r < 4; ++r)
                sSc[wid][lq * 4 + r] = p[r];
        }
        if (lane < 16) {
            const float s = sSc[wid][lane] * cinv;
            const float rn = 1.0f / sqrtf(dx * dx + dy * dy + dz * dz);
            const float sx = s * dx * rn, sy = s * dy * rn, sz = s * dz * rn;
            float* L = sLacc + g * 9;
            atomicAdd(L + 0, sx * dx); atomicAdd(L + 1, sx * dy); atomicAdd(L + 2, sx * dz);
            atomicAdd(L + 3, sy * dx); atomicAdd(L + 4, sy * dy); atomicAdd(L + 5, sy * dz);
            atomicAdd(L + 6, sz * dx); atomicAdd(L + 7, sz * dy); atomicAdd(L + 8, sz * dz);
        }
    }

    __syncthreads();
    for (int i = tid; i < NG * 9; i += 256)
        atomicAdd(&Lws[i], sLacc[i]);
}

// ---------------- kernel D: symmetrize ----------------
__global__ void gn_finalize(const float* __restrict__ Lws, float* __restrict__ out) {
    const int i = blockIdx.x * 256 + threadIdx.x;
    if (i < NG * 9) {
        const int g = i / 9, rem = i % 9, r = rem / 3, c = rem % 3;
        out[i] = 0.5f * (Lws[i] + Lws[g * 9 + c * 3 + r]);
    }
}

extern "C" void kernel_launch(void* const* d_in, const int* in_sizes, int n_in,
                              void* d_out, int out_size, void* d_ws, size_t ws_size,
                              hipStream_t stream) {
    const float* edge_emb = (const float*)d_in[0];
    const float* dvec     = (const float*)d_in[1];
    const float* rbf      = (const float*)d_in[3];
    const float* W1       = (const float*)d_in[4];
    const float* W2       = (const float*)d_in[5];
    const float* Wr       = (const float*)d_in[6];
    const float* Wo       = (const float*)d_in[7];
    const int*   ei0      = (const int*)d_in[8];
    const int*   batch    = (const int*)d_in[9];
    float* out = (float*)d_out;

    int*   counts = (int*)d_ws;                               // [0,1024)
    float* Lws    = (float*)((char*)d_ws + 1024);             // [1024,10240)
    unsigned char* fragW1 = (unsigned char*)d_ws + 10240;     // 32KB
    unsigned char* fragG  = (unsigned char*)d_ws + 43008;     // 8KB

    hipMemsetAsync(d_ws, 0, 10240, stream);
    gn_prep<<<32, 64, 0, stream>>>(W1, W2, Wr, Wo, fragW1, fragG);
    gn_count<<<256, 256, 0, stream>>>(ei0, batch, counts);
    gn_main<<<GRID_MAIN, 256, 0, stream>>>(edge_emb, dvec, rbf, ei0, batch, counts,
                                           fragW1, fragG, Lws);
    gn_finalize<<<9, 256, 0, stream>>>(Lws, out);
}